// Round 13
// baseline (493.636 us; speedup 1.0000x reference)
//
#include <hip/hip_runtime.h>

// ---------- types ----------
typedef short s16x8 __attribute__((ext_vector_type(8)));   // 8 bf16 (4 VGPRs)
typedef float f32x4 __attribute__((ext_vector_type(4)));

static __device__ __forceinline__ unsigned short f2bf(float f) {
  unsigned u = __builtin_bit_cast(unsigned, f);
  return (unsigned short)((u + 0x7FFFu + ((u >> 16) & 1u)) >> 16);   // RNE; finite
}

// async global->LDS, 16B per lane; LDS dst is wave-uniform base + lane*16
#define GLL16(G, L) __builtin_amdgcn_global_load_lds( \
    (const __attribute__((address_space(1))) void*)(G), \
    (__attribute__((address_space(3))) void*)(L), 16, 0, 0)

#define KD 512
// B=16, T=512, C=19, E=512, H=8, HD=64; groups = 8192, rows = 155648 = 1216*128.
// Fragment layout: frag (tile16, ktile32) = 1 KB: lane lf = (row&15) + 16*jc holds
// 16 B (8 bf16) of [row][ktile*32 + jc*8]. MFMA A/B reads are lane*16-linear.

// ---------- kernel: eeg fp32 -> bf16 fragment layout ----------
__global__ __launch_bounds__(256)
void k_conva(const float* __restrict__ src, unsigned short* __restrict__ dst) {
  int gid = blockIdx.x * 256 + threadIdx.x;
  int mt = gid >> 10, slot = gid & 1023;
  int kt = slot >> 6, lf = slot & 63;
  int row = mt * 16 + (lf & 15);
  int jc  = lf >> 4;
  const float* p = src + (long)row * KD + kt * 32 + jc * 8;
  float4 v0 = *(const float4*)p;
  float4 v1 = *(const float4*)(p + 4);
  s16x8 o;
  o[0]=(short)f2bf(v0.x); o[1]=(short)f2bf(v0.y); o[2]=(short)f2bf(v0.z); o[3]=(short)f2bf(v0.w);
  o[4]=(short)f2bf(v1.x); o[5]=(short)f2bf(v1.y); o[6]=(short)f2bf(v1.z); o[7]=(short)f2bf(v1.w);
  *(s16x8*)(dst + ((long)mt * 16 + kt) * 512 + (long)lf * 8) = o;
}

// ---------- kernel: weights fp32 -> bf16 fragment layout (rows 0..511 wq, 512..1023 wk) ----------
__global__ __launch_bounds__(256)
void k_convw(const float* __restrict__ wq, const float* __restrict__ wk,
             unsigned short* __restrict__ Wf) {
  int gid = blockIdx.x * 256 + threadIdx.x;   // 65536 threads
  int nt = gid >> 10, slot = gid & 1023;
  int kt = slot >> 6, lf = slot & 63;
  int f  = nt * 16 + (lf & 15);
  int jc = lf >> 4;
  const float* p = ((f < 512) ? (wq + (long)f * KD) : (wk + (long)(f - 512) * KD)) + kt * 32 + jc * 8;
  float4 v0 = *(const float4*)p;
  float4 v1 = *(const float4*)(p + 4);
  s16x8 o;
  o[0]=(short)f2bf(v0.x); o[1]=(short)f2bf(v0.y); o[2]=(short)f2bf(v0.z); o[3]=(short)f2bf(v0.w);
  o[4]=(short)f2bf(v1.x); o[5]=(short)f2bf(v1.y); o[6]=(short)f2bf(v1.z); o[7]=(short)f2bf(v1.w);
  *(s16x8*)(Wf + ((long)nt * 16 + kt) * 512 + (long)lf * 8) = o;
}

// ---------- kernel: QK = A @ [Wq^T | Wk^T] + bias ----------
// v8: depth-2 counted-vmcnt pipeline (T4). 3 staging buffers; STAGE(t+2) issued at
// top of step t; end-of-step s_waitcnt vmcnt(4) (counted, never 0 until drain) +
// raw s_barrier, sched_barrier(0) fences per rule 18. Loads fly ~2 full steps.
// LDS 48 KB -> 3 blocks/CU; launch_bounds(256,3) -> ~170 regs/wave, no spill.
__global__ __launch_bounds__(256, 3)
void k_gemm(const unsigned short* __restrict__ Af, const unsigned short* __restrict__ Wf,
            const float* __restrict__ bq, const float* __restrict__ bk,
            unsigned short* __restrict__ QK) {
  __shared__ unsigned short Abuf[3][8 * 512];   // 8 frags (msub 0..7) per buffer, BK=32
  __shared__ unsigned short Bbuf[3][8 * 512];   // 8 frags (nsub 0..7) per buffer

  const int tid  = threadIdx.x;
  const int lane = tid & 63;
  const int wid  = tid >> 6;      // 0..3
  const int wr   = wid >> 1, wc = wid & 1;
  const int rlo  = lane & 15, rhi = lane >> 4;

  // XCD-chunked swizzle (R8/R9 verified: A panel fetched ~once per XCD).
  const int cpx = gridDim.x >> 3;
  const int L   = (blockIdx.x & 7) * cpx + (blockIdx.x >> 3);
  const int mb  = L >> 3;
  const int bn  = L & 7;

#define STAGE(T, BUF) do { \
    if (wid < 2) { \
      _Pragma("unroll") for (int s = 0; s < 4; ++s) { \
        int msub = wid * 4 + s; \
        const unsigned short* g = Af + ((long)(mb * 8 + msub) * 16 + (T)) * 512 + lane * 8; \
        GLL16(g, &Abuf[(BUF)][msub * 512]); \
      } \
    } else { \
      _Pragma("unroll") for (int s = 0; s < 4; ++s) { \
        int nsub = (wid - 2) * 4 + s; \
        const unsigned short* g = Wf + ((long)(bn * 8 + nsub) * 16 + (T)) * 512 + lane * 8; \
        GLL16(g, &Bbuf[(BUF)][nsub * 512]); \
      } \
    } \
  } while (0)

  f32x4 acc[4][4] = {};
  // prologue: stage t0, t1; wait t0 only (counted), barrier
  STAGE(0, 0);
  STAGE(1, 1);
  asm volatile("s_waitcnt vmcnt(4)" ::: "memory");
  __builtin_amdgcn_sched_barrier(0);
  __builtin_amdgcn_s_barrier();
  __builtin_amdgcn_sched_barrier(0);

  int cur = 0;
#pragma unroll 1
  for (int t = 0; t < 16; ++t) {
    if (t < 14) {
      int stg = cur + 2; if (stg >= 3) stg -= 3;
      STAGE(t + 2, stg);                 // issue-early: 2 steps ahead
    }

    s16x8 af[4], bfr[4];
#pragma unroll
    for (int m = 0; m < 4; ++m)
      af[m] = *(const s16x8*)&Abuf[cur][(wr * 4 + m) * 512 + lane * 8];
#pragma unroll
    for (int n = 0; n < 4; ++n)
      bfr[n] = *(const s16x8*)&Bbuf[cur][(wc * 4 + n) * 512 + lane * 8];
#pragma unroll
    for (int m = 0; m < 4; ++m)
#pragma unroll
      for (int n = 0; n < 4; ++n)
        acc[m][n] = __builtin_amdgcn_mfma_f32_16x16x32_bf16(af[m], bfr[n], acc[m][n], 0, 0, 0);

    if (t < 15) {
      if (t < 14) asm volatile("s_waitcnt vmcnt(4)" ::: "memory");  // t+1 done; t+2 flying
      else        asm volatile("s_waitcnt vmcnt(0)" ::: "memory");  // final drain
      __builtin_amdgcn_sched_barrier(0);
      __builtin_amdgcn_s_barrier();
      __builtin_amdgcn_sched_barrier(0);
    }
    cur += 1; if (cur >= 3) cur -= 3;
  }
#undef STAGE

  // ---- epilogue: bias + bf16 store ----
#pragma unroll
  for (int n = 0; n < 4; ++n) {
    int colg = bn * 128 + wc * 64 + n * 16 + rlo;
    float bias = (colg < 512) ? bq[colg] : bk[colg - 512];
#pragma unroll
    for (int m = 0; m < 4; ++m) {
      long rl = (long)mb * 128 + wr * 64 + m * 16 + (rhi << 2);
#pragma unroll
      for (int j = 0; j < 4; ++j)
        QK[(rl + j) * 1024 + colg] = f2bf(acc[m][n][j] + bias);
    }
  }
}

// ---------- kernel: per-group attention (swapped-QK^T, row-local softmax) ----------
// v3: compute mfma(K, Q) so output col = q-row (lane-local). Each row's 19 scores
// live as 8 in-lane values x 4 rhi-lanes: reduction = in-lane ops + 2 shfl_xor per
// quantity (~24 shfl/thread total vs 192 in v2's col-layout version).
__global__ __launch_bounds__(256, 4)
void k_attn(const unsigned short* __restrict__ QK, float* __restrict__ acc, int g0) {
  __shared__ unsigned short Qs[19][1032];   // padded stride
  __shared__ float red[4];

  const int tid  = threadIdx.x;
  const int lane = tid & 63;
  const int wid  = tid >> 6;
  const long gl  = blockIdx.x;

  const unsigned short* src = QK + gl * 19 * 1024;
  for (int c = tid; c < 2432; c += 256) {
    int row = c >> 7, c8 = (c & 127) << 3;
    *(s16x8*)&Qs[row][c8] = *(const s16x8*)(src + row * 1024 + c8);
  }
  __syncthreads();

  const int rlo = lane & 15, rhi = lane >> 4;
  const s16x8 z8 = {};
  float psum = 0.f;

#pragma unroll
  for (int hh = 0; hh < 2; ++hh) {
    const int h = wid * 2 + hh;
    f32x4 s[2][2] = {};   // [k-tile mi][q-tile nj]
#pragma unroll
    for (int ks = 0; ks < 2; ++ks) {
      s16x8 qa[2], kb[2];
#pragma unroll
      for (int mi = 0; mi < 2; ++mi) {
        int r = mi * 16 + rlo;
        qa[mi] = (r < 19) ? *(const s16x8*)&Qs[r][h * 64 + ks * 32 + rhi * 8] : z8;
        kb[mi] = (r < 19) ? *(const s16x8*)&Qs[r][512 + h * 64 + ks * 32 + rhi * 8] : z8;
      }
#pragma unroll
      for (int mi = 0; mi < 2; ++mi)
#pragma unroll
        for (int nj = 0; nj < 2; ++nj)
          s[mi][nj] = __builtin_amdgcn_mfma_f32_16x16x32_bf16(kb[mi], qa[nj], s[mi][nj], 0, 0, 0);
    }

    // lane view: q = nj*16 + rlo; k = mi*16 + rhi*4 + j
#pragma unroll
    for (int nj = 0; nj < 2; ++nj) {
      const int q = nj * 16 + rlo;
      const bool qv = (q < 19);
      const bool wv = (rhi == 0);          // mi=1 rows k=16..18 live on rhi==0, j<3
      float v0 = s[0][nj][0] * 0.125f;     // k = rhi*4 + 0 (always < 16)
      float v1 = s[0][nj][1] * 0.125f;
      float v2 = s[0][nj][2] * 0.125f;
      float v3 = s[0][nj][3] * 0.125f;
      float w0 = s[1][nj][0] * 0.125f;     // k = 16,17,18 (rhi==0 only)
      float w1 = s[1][nj][1] * 0.125f;
      float w2 = s[1][nj][2] * 0.125f;
      float mm = fmaxf(fmaxf(v0, v1), fmaxf(v2, v3));
      if (wv) mm = fmaxf(mm, fmaxf(fmaxf(w0, w1), w2));
      mm = fmaxf(mm, __shfl_xor(mm, 16));
      mm = fmaxf(mm, __shfl_xor(mm, 32));
      float e0 = __expf(v0 - mm), e1 = __expf(v1 - mm);
      float e2 = __expf(v2 - mm), e3 = __expf(v3 - mm);
      float se = e0 + e1 + e2 + e3;
      int k0 = rhi * 4;
      float ue = ((k0 > q) ? e0 : 0.f) + ((k0 + 1 > q) ? e1 : 0.f)
               + ((k0 + 2 > q) ? e2 : 0.f) + ((k0 + 3 > q) ? e3 : 0.f);
      if (wv) {
        float f0 = __expf(w0 - mm), f1 = __expf(w1 - mm), f2 = __expf(w2 - mm);
        se += f0 + f1 + f2;
        ue += ((16 > q) ? f0 : 0.f) + ((17 > q) ? f1 : 0.f) + ((18 > q) ? f2 : 0.f);
      }
      se += __shfl_xor(se, 16); se += __shfl_xor(se, 32);
      ue += __shfl_xor(ue, 16); ue += __shfl_xor(ue, 32);
      if (qv && rhi == 0) psum += ue / se;
    }
  }

  // wave butterfly (psum nonzero on rhi==0 lanes only) -> block -> atomic
  psum += __shfl_xor(psum, 1);
  psum += __shfl_xor(psum, 2);
  psum += __shfl_xor(psum, 4);
  psum += __shfl_xor(psum, 8);
  psum += __shfl_xor(psum, 16);
  psum += __shfl_xor(psum, 32);
  if (lane == 0) red[wid] = psum;
  __syncthreads();
  if (tid == 0) {
    int b = (g0 + (int)blockIdx.x) >> 9;
    atomicAdd(&acc[b], red[0] + red[1] + red[2] + red[3]);
  }
}

// ---------- kernel: finalize out[b] = clip(acc[b] / (8*171*512), 0, 1) ----------
__global__ void k_fin(const float* __restrict__ acc, float* __restrict__ out) {
  int t = threadIdx.x;
  if (t < 16) {
    float v = acc[t] * (1.0f / 700416.0f);
    out[t] = fminf(1.0f, fmaxf(0.0f, v));
  }
}

// ---------- host ----------
extern "C" void kernel_launch(void* const* d_in, const int* in_sizes, int n_in,
                              void* d_out, int out_size, void* d_ws, size_t ws_size,
                              hipStream_t stream) {
  const float* eeg = (const float*)d_in[0];
  const float* wq  = (const float*)d_in[1];
  const float* wk  = (const float*)d_in[2];
  const float* bq  = (const float*)d_in[3];
  const float* bk  = (const float*)d_in[4];
  float* out = (float*)d_out;

  char* ws = (char*)d_ws;
  unsigned short* Wf = (unsigned short*)ws;          // 1 MiB frag-layout weights
  float* acc = (float*)(ws + (1 << 20));             // 64 B accumulators
  long off = (1 << 20) + 256;

  // per-group: Af 19456 B, QK 38912 B. Single chunk when ws permits (R7 lesson).
  long avail = (long)ws_size - off;
  long G = avail / 58368;
  G = (G / 128) * 128;
  if (G > 8192) G = 8192;
  if (G < 128) G = 128;
  unsigned short* Afb = (unsigned short*)(ws + off);
  unsigned short* QKb = (unsigned short*)(ws + off + G * 19456L);

  hipMemsetAsync(acc, 0, 64, stream);
  k_convw<<<256, 256, 0, stream>>>(wq, wk, Wf);

  for (int g0 = 0; g0 < 8192; g0 += (int)G) {
    int cg = 8192 - g0; if (cg > (int)G) cg = (int)G;
    int rows   = cg * 19;            // cg multiple of 128 -> rows multiple of 2432
    int mtiles = rows / 16;
    k_conva<<<mtiles * 4, 256, 0, stream>>>(eeg + (long)g0 * 19 * KD, Afb);
    k_gemm<<<(rows / 128) * 8, 256, 0, stream>>>(Afb, Wf, bq, bk, QKb);
    k_attn<<<cg, 256, 0, stream>>>(QKb, acc, g0);
  }
  k_fin<<<1, 64, 0, stream>>>(acc, out);
}

// Round 14
// 465.476 us; speedup vs baseline: 1.0605x; 1.0605x over previous
//
#include <hip/hip_runtime.h>

// ---------- types ----------
typedef short s16x8 __attribute__((ext_vector_type(8)));   // 8 bf16 (4 VGPRs)
typedef float f32x4 __attribute__((ext_vector_type(4)));

static __device__ __forceinline__ unsigned short f2bf(float f) {
  unsigned u = __builtin_bit_cast(unsigned, f);
  return (unsigned short)((u + 0x7FFFu + ((u >> 16) & 1u)) >> 16);   // RNE; finite
}

// async global->LDS, 16B per lane; LDS dst is wave-uniform base + lane*16
#define GLL16(G, L) __builtin_amdgcn_global_load_lds( \
    (const __attribute__((address_space(1))) void*)(G), \
    (__attribute__((address_space(3))) void*)(L), 16, 0, 0)

#define KD 512
// B=16, T=512, C=19, E=512, H=8, HD=64; groups = 8192, rows = 155648 = 1216*128.
// Fragment layout: frag (tile16, ktile32) = 1 KB: lane lf = (row&15) + 16*jc holds
// 16 B (8 bf16) of [row][ktile*32 + jc*8]. MFMA A/B reads are lane*16-linear.

// ---------- kernel: eeg fp32 -> bf16 fragment layout ----------
__global__ __launch_bounds__(256)
void k_conva(const float* __restrict__ src, unsigned short* __restrict__ dst) {
  int gid = blockIdx.x * 256 + threadIdx.x;
  int mt = gid >> 10, slot = gid & 1023;
  int kt = slot >> 6, lf = slot & 63;
  int row = mt * 16 + (lf & 15);
  int jc  = lf >> 4;
  const float* p = src + (long)row * KD + kt * 32 + jc * 8;
  float4 v0 = *(const float4*)p;
  float4 v1 = *(const float4*)(p + 4);
  s16x8 o;
  o[0]=(short)f2bf(v0.x); o[1]=(short)f2bf(v0.y); o[2]=(short)f2bf(v0.z); o[3]=(short)f2bf(v0.w);
  o[4]=(short)f2bf(v1.x); o[5]=(short)f2bf(v1.y); o[6]=(short)f2bf(v1.z); o[7]=(short)f2bf(v1.w);
  *(s16x8*)(dst + ((long)mt * 16 + kt) * 512 + (long)lf * 8) = o;
}

// ---------- kernel: weights fp32 -> bf16 fragment layout (rows 0..511 wq, 512..1023 wk) ----------
__global__ __launch_bounds__(256)
void k_convw(const float* __restrict__ wq, const float* __restrict__ wk,
             unsigned short* __restrict__ Wf) {
  int gid = blockIdx.x * 256 + threadIdx.x;   // 65536 threads
  int nt = gid >> 10, slot = gid & 1023;
  int kt = slot >> 6, lf = slot & 63;
  int f  = nt * 16 + (lf & 15);
  int jc = lf >> 4;
  const float* p = ((f < 512) ? (wq + (long)f * KD) : (wk + (long)(f - 512) * KD)) + kt * 32 + jc * 8;
  float4 v0 = *(const float4*)p;
  float4 v1 = *(const float4*)(p + 4);
  s16x8 o;
  o[0]=(short)f2bf(v0.x); o[1]=(short)f2bf(v0.y); o[2]=(short)f2bf(v0.z); o[3]=(short)f2bf(v0.w);
  o[4]=(short)f2bf(v1.x); o[5]=(short)f2bf(v1.y); o[6]=(short)f2bf(v1.z); o[7]=(short)f2bf(v1.w);
  *(s16x8*)(Wf + ((long)nt * 16 + kt) * 512 + (long)lf * 8) = o;
}

// ---------- kernel: QK = A @ [Wq^T | Wk^T] + bias ----------
// v9: LDS-BW diet. Per-step per-CU LDS reads were 32x ds_read_b128 (~384cyc) vs 77cyc
// MFMA -> LDS-throughput-bound (explains R9/R10/R12/R13 all ~240-290). Fix: B frags
// come straight from L2-resident Wf into NAMED regs (cb/nb depth-1 rotation, unroll-2,
// rule-#20-safe); only A goes through LDS (gload_lds, 2x8KB dbuf). 16 LDS reads/step.
__global__ __launch_bounds__(256, 3)
void k_gemm(const unsigned short* __restrict__ Af, const unsigned short* __restrict__ Wf,
            const float* __restrict__ bq, const float* __restrict__ bk,
            unsigned short* __restrict__ QK) {
  __shared__ unsigned short Abuf[2][8 * 512];   // 8 frags (msub 0..7) per buffer

  const int tid  = threadIdx.x;
  const int lane = tid & 63;
  const int wid  = tid >> 6;      // 0..3
  const int wr   = wid >> 1, wc = wid & 1;
  const int rlo  = lane & 15, rhi = lane >> 4;

  // XCD-chunked swizzle (R8/R9 verified: A panel fetched ~once per XCD).
  const int cpx = gridDim.x >> 3;
  const int L   = (blockIdx.x & 7) * cpx + (blockIdx.x >> 3);
  const int mb  = L >> 3;
  const int bn  = L & 7;

  // B: this wave's 4 col-tiles, read per-step at bpX + t*512 (16B/lane, L2-resident)
  const unsigned short* bp0 = Wf + ((long)(bn * 8 + wc * 4) * 16) * 512 + lane * 8;
  const unsigned short* bp1 = bp0 + 16 * 512;
  const unsigned short* bp2 = bp0 + 32 * 512;
  const unsigned short* bp3 = bp0 + 48 * 512;

  // A staging: wave stages frags {2*wid, 2*wid+1} via global_load_lds
#define STAGE_A(T, BUF) do { \
    const unsigned short* ga0_ = Af + ((long)(mb * 8 + wid * 2) * 16 + (T)) * 512 + lane * 8; \
    GLL16(ga0_, &Abuf[(BUF)][(wid * 2) * 512]); \
    const unsigned short* ga1_ = Af + ((long)(mb * 8 + wid * 2 + 1) * 16 + (T)) * 512 + lane * 8; \
    GLL16(ga1_, &Abuf[(BUF)][(wid * 2 + 1) * 512]); \
  } while (0)

#define COMPUTE(CUR, B0, B1, B2, B3) do { \
    s16x8 af0 = *(const s16x8*)&Abuf[(CUR)][(wr * 4 + 0) * 512 + lane * 8]; \
    s16x8 af1 = *(const s16x8*)&Abuf[(CUR)][(wr * 4 + 1) * 512 + lane * 8]; \
    s16x8 af2 = *(const s16x8*)&Abuf[(CUR)][(wr * 4 + 2) * 512 + lane * 8]; \
    s16x8 af3 = *(const s16x8*)&Abuf[(CUR)][(wr * 4 + 3) * 512 + lane * 8]; \
    acc[0][0] = __builtin_amdgcn_mfma_f32_16x16x32_bf16(af0, B0, acc[0][0], 0, 0, 0); \
    acc[0][1] = __builtin_amdgcn_mfma_f32_16x16x32_bf16(af0, B1, acc[0][1], 0, 0, 0); \
    acc[0][2] = __builtin_amdgcn_mfma_f32_16x16x32_bf16(af0, B2, acc[0][2], 0, 0, 0); \
    acc[0][3] = __builtin_amdgcn_mfma_f32_16x16x32_bf16(af0, B3, acc[0][3], 0, 0, 0); \
    acc[1][0] = __builtin_amdgcn_mfma_f32_16x16x32_bf16(af1, B0, acc[1][0], 0, 0, 0); \
    acc[1][1] = __builtin_amdgcn_mfma_f32_16x16x32_bf16(af1, B1, acc[1][1], 0, 0, 0); \
    acc[1][2] = __builtin_amdgcn_mfma_f32_16x16x32_bf16(af1, B2, acc[1][2], 0, 0, 0); \
    acc[1][3] = __builtin_amdgcn_mfma_f32_16x16x32_bf16(af1, B3, acc[1][3], 0, 0, 0); \
    acc[2][0] = __builtin_amdgcn_mfma_f32_16x16x32_bf16(af2, B0, acc[2][0], 0, 0, 0); \
    acc[2][1] = __builtin_amdgcn_mfma_f32_16x16x32_bf16(af2, B1, acc[2][1], 0, 0, 0); \
    acc[2][2] = __builtin_amdgcn_mfma_f32_16x16x32_bf16(af2, B2, acc[2][2], 0, 0, 0); \
    acc[2][3] = __builtin_amdgcn_mfma_f32_16x16x32_bf16(af2, B3, acc[2][3], 0, 0, 0); \
    acc[3][0] = __builtin_amdgcn_mfma_f32_16x16x32_bf16(af3, B0, acc[3][0], 0, 0, 0); \
    acc[3][1] = __builtin_amdgcn_mfma_f32_16x16x32_bf16(af3, B1, acc[3][1], 0, 0, 0); \
    acc[3][2] = __builtin_amdgcn_mfma_f32_16x16x32_bf16(af3, B2, acc[3][2], 0, 0, 0); \
    acc[3][3] = __builtin_amdgcn_mfma_f32_16x16x32_bf16(af3, B3, acc[3][3], 0, 0, 0); \
  } while (0)

  f32x4 acc[4][4] = {};

  // prologue: B(t=0) into cb, A(t=0) into buf0
  s16x8 cb0 = *(const s16x8*)(bp0);
  s16x8 cb1 = *(const s16x8*)(bp1);
  s16x8 cb2 = *(const s16x8*)(bp2);
  s16x8 cb3 = *(const s16x8*)(bp3);
  STAGE_A(0, 0);
  __syncthreads();   // drains vmcnt(0): buf0 + cb ready

#pragma unroll 1
  for (int t2 = 0; t2 < 8; ++t2) {
    const int t = t2 * 2;
    // even step t: reads Abuf[0] + cb; prefetch B(t+1)->nb, A(t+1)->buf1
    s16x8 nb0 = *(const s16x8*)(bp0 + (t + 1) * 512);
    s16x8 nb1 = *(const s16x8*)(bp1 + (t + 1) * 512);
    s16x8 nb2 = *(const s16x8*)(bp2 + (t + 1) * 512);
    s16x8 nb3 = *(const s16x8*)(bp3 + (t + 1) * 512);
    STAGE_A(t + 1, 1);
    COMPUTE(0, cb0, cb1, cb2, cb3);
    __syncthreads();   // buf1 + nb drained; all reads of buf0 done

    // odd step t+1: reads Abuf[1] + nb; prefetch B(t+2)->cb, A(t+2)->buf0
    if (t2 < 7) {
      cb0 = *(const s16x8*)(bp0 + (t + 2) * 512);
      cb1 = *(const s16x8*)(bp1 + (t + 2) * 512);
      cb2 = *(const s16x8*)(bp2 + (t + 2) * 512);
      cb3 = *(const s16x8*)(bp3 + (t + 2) * 512);
      STAGE_A(t + 2, 0);
    }
    COMPUTE(1, nb0, nb1, nb2, nb3);
    if (t2 < 7) __syncthreads();
  }
#undef STAGE_A
#undef COMPUTE

  // ---- epilogue: bias + bf16 store ----
#pragma unroll
  for (int n = 0; n < 4; ++n) {
    int colg = bn * 128 + wc * 64 + n * 16 + rlo;
    float bias = (colg < 512) ? bq[colg] : bk[colg - 512];
#pragma unroll
    for (int m = 0; m < 4; ++m) {
      long rl = (long)mb * 128 + wr * 64 + m * 16 + (rhi << 2);
#pragma unroll
      for (int j = 0; j < 4; ++j)
        QK[(rl + j) * 1024 + colg] = f2bf(acc[m][n][j] + bias);
    }
  }
}

// ---------- kernel: per-group attention (swapped-QK^T, row-local softmax) ----------
// v3 (kept from R13, ~30 us better than v2): mfma(K,Q) puts q-row in lane; reduction
// is in-lane + 2 shfl_xor per quantity.
__global__ __launch_bounds__(256, 4)
void k_attn(const unsigned short* __restrict__ QK, float* __restrict__ acc, int g0) {
  __shared__ unsigned short Qs[19][1032];   // padded stride
  __shared__ float red[4];

  const int tid  = threadIdx.x;
  const int lane = tid & 63;
  const int wid  = tid >> 6;
  const long gl  = blockIdx.x;

  const unsigned short* src = QK + gl * 19 * 1024;
  for (int c = tid; c < 2432; c += 256) {
    int row = c >> 7, c8 = (c & 127) << 3;
    *(s16x8*)&Qs[row][c8] = *(const s16x8*)(src + row * 1024 + c8);
  }
  __syncthreads();

  const int rlo = lane & 15, rhi = lane >> 4;
  const s16x8 z8 = {};
  float psum = 0.f;

#pragma unroll
  for (int hh = 0; hh < 2; ++hh) {
    const int h = wid * 2 + hh;
    f32x4 s[2][2] = {};   // [k-tile mi][q-tile nj]
#pragma unroll
    for (int ks = 0; ks < 2; ++ks) {
      s16x8 qa[2], kb[2];
#pragma unroll
      for (int mi = 0; mi < 2; ++mi) {
        int r = mi * 16 + rlo;
        qa[mi] = (r < 19) ? *(const s16x8*)&Qs[r][h * 64 + ks * 32 + rhi * 8] : z8;
        kb[mi] = (r < 19) ? *(const s16x8*)&Qs[r][512 + h * 64 + ks * 32 + rhi * 8] : z8;
      }
#pragma unroll
      for (int mi = 0; mi < 2; ++mi)
#pragma unroll
        for (int nj = 0; nj < 2; ++nj)
          s[mi][nj] = __builtin_amdgcn_mfma_f32_16x16x32_bf16(kb[mi], qa[nj], s[mi][nj], 0, 0, 0);
    }

    // lane view: q = nj*16 + rlo; k = mi*16 + rhi*4 + j
#pragma unroll
    for (int nj = 0; nj < 2; ++nj) {
      const int q = nj * 16 + rlo;
      const bool qv = (q < 19);
      const bool wv = (rhi == 0);          // k=16..18 live on rhi==0
      float v0 = s[0][nj][0] * 0.125f;
      float v1 = s[0][nj][1] * 0.125f;
      float v2 = s[0][nj][2] * 0.125f;
      float v3 = s[0][nj][3] * 0.125f;
      float w0 = s[1][nj][0] * 0.125f;
      float w1 = s[1][nj][1] * 0.125f;
      float w2 = s[1][nj][2] * 0.125f;
      float mm = fmaxf(fmaxf(v0, v1), fmaxf(v2, v3));
      if (wv) mm = fmaxf(mm, fmaxf(fmaxf(w0, w1), w2));
      mm = fmaxf(mm, __shfl_xor(mm, 16));
      mm = fmaxf(mm, __shfl_xor(mm, 32));
      float e0 = __expf(v0 - mm), e1 = __expf(v1 - mm);
      float e2 = __expf(v2 - mm), e3 = __expf(v3 - mm);
      float se = e0 + e1 + e2 + e3;
      int k0 = rhi * 4;
      float ue = ((k0 > q) ? e0 : 0.f) + ((k0 + 1 > q) ? e1 : 0.f)
               + ((k0 + 2 > q) ? e2 : 0.f) + ((k0 + 3 > q) ? e3 : 0.f);
      if (wv) {
        float f0 = __expf(w0 - mm), f1 = __expf(w1 - mm), f2 = __expf(w2 - mm);
        se += f0 + f1 + f2;
        ue += ((16 > q) ? f0 : 0.f) + ((17 > q) ? f1 : 0.f) + ((18 > q) ? f2 : 0.f);
      }
      se += __shfl_xor(se, 16); se += __shfl_xor(se, 32);
      ue += __shfl_xor(ue, 16); ue += __shfl_xor(ue, 32);
      if (qv && rhi == 0) psum += ue / se;
    }
  }

  psum += __shfl_xor(psum, 1);
  psum += __shfl_xor(psum, 2);
  psum += __shfl_xor(psum, 4);
  psum += __shfl_xor(psum, 8);
  psum += __shfl_xor(psum, 16);
  psum += __shfl_xor(psum, 32);
  if (lane == 0) red[wid] = psum;
  __syncthreads();
  if (tid == 0) {
    int b = (g0 + (int)blockIdx.x) >> 9;
    atomicAdd(&acc[b], red[0] + red[1] + red[2] + red[3]);
  }
}

// ---------- kernel: finalize out[b] = clip(acc[b] / (8*171*512), 0, 1) ----------
__global__ void k_fin(const float* __restrict__ acc, float* __restrict__ out) {
  int t = threadIdx.x;
  if (t < 16) {
    float v = acc[t] * (1.0f / 700416.0f);
    out[t] = fminf(1.0f, fmaxf(0.0f, v));
  }
}

// ---------- host ----------
extern "C" void kernel_launch(void* const* d_in, const int* in_sizes, int n_in,
                              void* d_out, int out_size, void* d_ws, size_t ws_size,
                              hipStream_t stream) {
  const float* eeg = (const float*)d_in[0];
  const float* wq  = (const float*)d_in[1];
  const float* wk  = (const float*)d_in[2];
  const float* bq  = (const float*)d_in[3];
  const float* bk  = (const float*)d_in[4];
  float* out = (float*)d_out;

  char* ws = (char*)d_ws;
  unsigned short* Wf = (unsigned short*)ws;          // 1 MiB frag-layout weights
  float* acc = (float*)(ws + (1 << 20));             // 64 B accumulators
  long off = (1 << 20) + 256;

  // per-group: Af 19456 B, QK 38912 B. Single chunk when ws permits (R7 lesson).
  long avail = (long)ws_size - off;
  long G = avail / 58368;
  G = (G / 128) * 128;
  if (G > 8192) G = 8192;
  if (G < 128) G = 128;
  unsigned short* Afb = (unsigned short*)(ws + off);
  unsigned short* QKb = (unsigned short*)(ws + off + G * 19456L);

  hipMemsetAsync(acc, 0, 64, stream);
  k_convw<<<256, 256, 0, stream>>>(wq, wk, Wf);

  for (int g0 = 0; g0 < 8192; g0 += (int)G) {
    int cg = 8192 - g0; if (cg > (int)G) cg = (int)G;
    int rows   = cg * 19;            // cg multiple of 128 -> rows multiple of 2432
    int mtiles = rows / 16;
    k_conva<<<mtiles * 4, 256, 0, stream>>>(eeg + (long)g0 * 19 * KD, Afb);
    k_gemm<<<(rows / 128) * 8, 256, 0, stream>>>(Afb, Wf, bq, bk, QKb);
    k_attn<<<cg, 256, 0, stream>>>(QKb, acc, g0);
  }
  k_fin<<<1, 64, 0, stream>>>(acc, out);
}